// Round 21
// baseline (230.543 us; speedup 1.0000x reference)
//
#include <hip/hip_runtime.h>
#include <stdint.h>
#include <stddef.h>

#define BATCH 65536
#define OUTF  1024
#define INF   128

typedef float f32x4 __attribute__((ext_vector_type(4)));
typedef __bf16 bf16x8 __attribute__((ext_vector_type(8)));

#define CPAD 132   // wave scratch row stride (floats): 128 + 4

// RNE float->bf16, packed pair
__device__ inline uint32_t pack_bf16_rne(float a, float b) {
    uint32_t ua = __builtin_bit_cast(uint32_t, a);
    uint32_t ub = __builtin_bit_cast(uint32_t, b);
    ua += 0x7fffu + ((ua >> 16) & 1u);
    ub += 0x7fffu + ((ub >> 16) & 1u);
    return (ua >> 16) | (ub & 0xffff0000u);
}

// Load 8 contiguous fp32, accumulate sum of squares, return bf16x8 fragment.
__device__ inline bf16x8 load_frag_x2(const float* __restrict__ p, float& s) {
    f32x4 v0 = *(const f32x4*)(p);
    f32x4 v1 = *(const f32x4*)(p + 4);
    s += v0.x * v0.x + v0.y * v0.y + v0.z * v0.z + v0.w * v0.w
       + v1.x * v1.x + v1.y * v1.y + v1.z * v1.z + v1.w * v1.w;
    union { uint32_t u[4]; bf16x8 b; } f;
    f.u[0] = pack_bf16_rne(v0.x, v0.y);
    f.u[1] = pack_bf16_rne(v0.z, v0.w);
    f.u[2] = pack_bf16_rne(v1.x, v1.y);
    f.u[3] = pack_bf16_rne(v1.z, v1.w);
    return f.b;
}

// W prep: one wave per w-row. Writes wb in MFMA FRAGMENT ORDER (R14-verified)
// + row sumsq. Tile t=row>>4, ks=k>>5, frag-lane wl=((k>>3)&3)*16+(row&15),
// elem j=k&7: bf16 addr = ((t*4+ks)*64 + wl)*8 + j -> GEMM B-fragment load
// is ONE contiguous 1KB instruction.
__global__ __launch_bounds__(256) void wprep_kernel(
        const float* __restrict__ w, float* __restrict__ w2,
        uint32_t* __restrict__ wb) {
    int gtid = blockIdx.x * 256 + threadIdx.x;
    int row  = gtid >> 6;
    int lane = threadIdx.x & 63;
    if (row >= OUTF) return;
    const float* src = w + (size_t)row * INF;
    float2 v = *(const float2*)(src + lane * 2);   // k = 2*lane, 2*lane+1
    int t    = row >> 4;
    int l16r = row & 15;
    int ks   = lane >> 4;
    int lq   = (lane >> 2) & 3;
    int sub  = lane & 3;
    wb[(((size_t)t * 4 + ks) * 64 + lq * 16 + l16r) * 4 + sub] =
        pack_bf16_rne(v.x, v.y);
    float s = v.x * v.x + v.y * v.y;
    #pragma unroll
    for (int off = 32; off; off >>= 1) s += __shfl_down(s, off);
    if (lane == 0) w2[row] = s;
}

// Persistent-ish fused kernel (R20 + 4 row-tiles per block): grid 1024
// (4/CU), block = 64 x-rows x ALL 1024 cols, looped as 4 tiles of 16 rows.
// 4x fewer prologues/barriers and 4x longer per-wave store streams vs R20;
// everything else identical (frag-order wb 1KB B-loads, in-block 1x x-cvt,
// wave-private LDS epilogue, paired 512B-segment NT stores).
__global__ __launch_bounds__(256, 4) void fused_kernel(
        const float* __restrict__ x, const __bf16* __restrict__ wb,
        const float* __restrict__ w2, float* __restrict__ out) {
    int tid  = threadIdx.x;
    int wid  = tid >> 6;        // wave -> col slice [wid*256, wid*256+256)
    int lane = tid & 63;
    int l16  = lane & 15;       // fragment row/col
    int lq   = lane >> 4;       // k-quarter (loads) / row-quad (epilogue)

    __shared__ float sw2[OUTF];
    __shared__ float scratch[4][16 * CPAD];   // per-wave [16][132]
    #pragma unroll
    for (int j = 0; j < 4; ++j)
        sw2[tid + 256 * j] = w2[tid + 256 * j];
    __syncthreads();   // sw2 ready — the ONLY barrier

    float* buf = scratch[wid];

    for (int g = 0; g < 4; ++g) {
        int rbase = blockIdx.x * 64 + g * 16;   // this tile's 16 x-rows

        // A fragments: 16 rows, k = ks*32 + lq*8 (16 VGPR) + x2 partial.
        bf16x8 a[4];
        float x2p = 0.f;
        #pragma unroll
        for (int ks = 0; ks < 4; ++ks)
            a[ks] = load_frag_x2(
                &x[(size_t)(rbase + l16) * INF + ks * 32 + lq * 8], x2p);

        // Row sumsq butterfly; redistribute to epilogue rows lq*4+r.
        x2p += __shfl_xor(x2p, 16);
        x2p += __shfl_xor(x2p, 32);
        float x2row[4];
        #pragma unroll
        for (int r = 0; r < 4; ++r)
            x2row[r] = __shfl(x2p, lq * 20 + r);

        #pragma unroll
        for (int sc = 0; sc < 4; ++sc) {
            int c0  = wid * 256 + sc * 64;          // sub-chunk column base
            int tb0 = c0 >> 4;                      // fragment-tile base
            int cb  = (sc & 1) * 64;                // column offset within buf

            f32x4 acc[4];
            #pragma unroll
            for (int in = 0; in < 4; ++in)
                acc[in] = f32x4{0.f, 0.f, 0.f, 0.f};

            #pragma unroll
            for (int ks = 0; ks < 4; ++ks) {
                bf16x8 b[4];
                #pragma unroll
                for (int in = 0; in < 4; ++in)
                    b[in] = *(const bf16x8*)(
                        wb + (((size_t)(tb0 + in) * 4 + ks) << 9) + lane * 8);
                #pragma unroll
                for (int in = 0; in < 4; ++in)
                    acc[in] = __builtin_amdgcn_mfma_f32_16x16x32_bf16(
                        a[ks], b[in], acc[in], 0, 0, 0);
            }

            // Epilogue into wave-private scratch (C/D: col=l16, row=lq*4+r).
            #pragma unroll
            for (int in = 0; in < 4; ++in) {
                #pragma unroll
                for (int r = 0; r < 4; ++r) {
                    int row = lq * 4 + r;                 // 0..15
                    int col = cb + in * 16 + l16;         // 0..127
                    float d2 = x2row[r] + sw2[c0 + col - cb] - 2.0f * acc[in][r];
                    buf[row * CPAD + col] =
                        -0.5f * __builtin_amdgcn_sqrtf(fmaxf(d2, 0.0f));
                }
            }
            // Intra-wave ds_write->ds_read ordering via lgkmcnt; no barrier.

            // After each PAIR of sub-chunks: 16 rows x 512B segments,
            // each NT inst = 1KB = 2 rows x 512B.
            if (sc & 1) {
                int cp0 = wid * 256 + (sc >> 1) * 128;
                #pragma unroll
                for (int k = 0; k < 8; ++k) {
                    int row = k * 2 + (lane >> 5);
                    f32x4 v = *(const f32x4*)&buf[row * CPAD + (lane & 31) * 4];
                    __builtin_nontemporal_store(
                        v, (f32x4*)&out[(size_t)(rbase + row) * OUTF + cp0 + (lane & 31) * 4]);
                }
            }
        }
    }
}

extern "C" void kernel_launch(void* const* d_in, const int* in_sizes, int n_in,
                              void* d_out, int out_size, void* d_ws, size_t ws_size,
                              hipStream_t stream) {
    const float* x = (const float*)d_in[0];
    const float* w = (const float*)d_in[1];
    float* out = (float*)d_out;

    // ws layout: w2 [1024 f32] at 0; wb (frag-order bf16 W, 256KB) at 4096.
    char* ws = (char*)d_ws;
    float* w2 = (float*)ws;
    uint32_t* wb_u32 = (uint32_t*)(ws + 4096);
    const __bf16* wb = (const __bf16*)wb_u32;

    wprep_kernel<<<dim3(OUTF / 4), dim3(256), 0, stream>>>(w, w2, wb_u32);
    fused_kernel<<<dim3(BATCH / 64), dim3(256), 0, stream>>>(x, wb, w2, out);
}

// Round 22
// 90.924 us; speedup vs baseline: 2.5356x; 2.5356x over previous
//
#include <hip/hip_runtime.h>
#include <stdint.h>
#include <stddef.h>

#define BATCH 65536
#define OUTF  1024
#define INF   128

typedef float f32x4 __attribute__((ext_vector_type(4)));
typedef __bf16 bf16x8 __attribute__((ext_vector_type(8)));

#define CPAD 68   // wave scratch row stride (floats): 64 + 4

// RNE float->bf16, packed pair
__device__ inline uint32_t pack_bf16_rne(float a, float b) {
    uint32_t ua = __builtin_bit_cast(uint32_t, a);
    uint32_t ub = __builtin_bit_cast(uint32_t, b);
    ua += 0x7fffu + ((ua >> 16) & 1u);
    ub += 0x7fffu + ((ub >> 16) & 1u);
    return (ua >> 16) | (ub & 0xffff0000u);
}

// Load 8 contiguous fp32, accumulate sum of squares, return bf16x8 fragment.
__device__ inline bf16x8 load_frag_x2(const float* __restrict__ p, float& s) {
    f32x4 v0 = *(const f32x4*)(p);
    f32x4 v1 = *(const f32x4*)(p + 4);
    s += v0.x * v0.x + v0.y * v0.y + v0.z * v0.z + v0.w * v0.w
       + v1.x * v1.x + v1.y * v1.y + v1.z * v1.z + v1.w * v1.w;
    union { uint32_t u[4]; bf16x8 b; } f;
    f.u[0] = pack_bf16_rne(v0.x, v0.y);
    f.u[1] = pack_bf16_rne(v0.z, v0.w);
    f.u[2] = pack_bf16_rne(v1.x, v1.y);
    f.u[3] = pack_bf16_rne(v1.z, v1.w);
    return f.b;
}

// W prep: one wave per w-row. Writes wb in MFMA FRAGMENT ORDER (R14-verified)
// + row sumsq. Tile t=row>>4, ks=k>>5, frag-lane wl=((k>>3)&3)*16+(row&15),
// elem j=k&7: bf16 addr = ((t*4+ks)*64 + wl)*8 + j -> GEMM B-fragment load
// is ONE contiguous 1KB instruction.
__global__ __launch_bounds__(256) void wprep_kernel(
        const float* __restrict__ w, float* __restrict__ w2,
        uint32_t* __restrict__ wb) {
    int gtid = blockIdx.x * 256 + threadIdx.x;
    int row  = gtid >> 6;
    int lane = threadIdx.x & 63;
    if (row >= OUTF) return;
    const float* src = w + (size_t)row * INF;
    float2 v = *(const float2*)(src + lane * 2);   // k = 2*lane, 2*lane+1
    int t    = row >> 4;
    int l16r = row & 15;
    int ks   = lane >> 4;
    int lq   = (lane >> 2) & 3;
    int sub  = lane & 3;
    wb[(((size_t)t * 4 + ks) * 64 + lq * 16 + l16r) * 4 + sub] =
        pack_bf16_rne(v.x, v.y);
    float s = v.x * v.x + v.y * v.y;
    #pragma unroll
    for (int off = 32; off; off >>= 1) s += __shfl_down(s, off);
    if (lane == 0) w2[row] = s;
}

// Fused kernel (R20 structure, 8-wave blocks -> 32 waves/CU full occupancy):
// block = 16 x-rows x ALL 1024 cols (grid 4096, 4 blocks/CU). 512 threads;
// wave owns a 128-col slice as 2 sub-chunks of 64. x converted in-block once;
// B-frags contiguous 1KB loads from frag-order wb; epilogue -> wave-private
// LDS scratch; NT f32x4 stores (256B segments, 1KB/inst) per sub-chunk.
// ONE barrier total (sw2 staging).
__global__ __launch_bounds__(512, 8) void fused_kernel(
        const float* __restrict__ x, const __bf16* __restrict__ wb,
        const float* __restrict__ w2, float* __restrict__ out) {
    int tid  = threadIdx.x;
    int wid  = tid >> 6;        // wave -> col slice [wid*128, wid*128+128)
    int lane = tid & 63;
    int l16  = lane & 15;       // fragment row/col
    int lq   = lane >> 4;       // k-quarter (loads) / row-quad (epilogue)

    int rbase = blockIdx.x * 16;   // block's 16 x-rows

    __shared__ float sw2[OUTF];
    __shared__ float scratch[8][16 * CPAD];   // per-wave [16][68]
    sw2[tid]       = w2[tid];
    sw2[tid + 512] = w2[tid + 512];

    // A fragments: 16 rows, k = ks*32 + lq*8 (16 VGPR) + x2 partial.
    bf16x8 a[4];
    float x2p = 0.f;
    #pragma unroll
    for (int ks = 0; ks < 4; ++ks)
        a[ks] = load_frag_x2(
            &x[(size_t)(rbase + l16) * INF + ks * 32 + lq * 8], x2p);

    // Row sumsq butterfly over k-quarter groups; redistribute to epilogue rows.
    x2p += __shfl_xor(x2p, 16);
    x2p += __shfl_xor(x2p, 32);
    float x2row[4];
    #pragma unroll
    for (int r = 0; r < 4; ++r)
        x2row[r] = __shfl(x2p, lq * 20 + r);

    __syncthreads();   // sw2 ready — the ONLY barrier

    float* buf = scratch[wid];

    #pragma unroll
    for (int sc = 0; sc < 2; ++sc) {
        int c0  = wid * 128 + sc * 64;          // sub-chunk column base
        int tb0 = c0 >> 4;                      // fragment-tile base

        f32x4 acc[4];
        #pragma unroll
        for (int in = 0; in < 4; ++in)
            acc[in] = f32x4{0.f, 0.f, 0.f, 0.f};

        #pragma unroll
        for (int ks = 0; ks < 4; ++ks) {
            bf16x8 b[4];
            #pragma unroll
            for (int in = 0; in < 4; ++in)
                b[in] = *(const bf16x8*)(
                    wb + (((size_t)(tb0 + in) * 4 + ks) << 9) + lane * 8);
            #pragma unroll
            for (int in = 0; in < 4; ++in)
                acc[in] = __builtin_amdgcn_mfma_f32_16x16x32_bf16(
                    a[ks], b[in], acc[in], 0, 0, 0);
        }

        // Epilogue into wave-private scratch (C/D: col=l16, row=lq*4+r).
        #pragma unroll
        for (int in = 0; in < 4; ++in) {
            #pragma unroll
            for (int r = 0; r < 4; ++r) {
                int row = lq * 4 + r;                 // 0..15
                int col = in * 16 + l16;              // 0..63
                float d2 = x2row[r] + sw2[c0 + col] - 2.0f * acc[in][r];
                buf[row * CPAD + col] =
                    -0.5f * __builtin_amdgcn_sqrtf(fmaxf(d2, 0.0f));
            }
        }
        // Intra-wave ds_write->ds_read ordering via lgkmcnt; no barrier.

        // Store sub-chunk: 16 rows x 256B segments; each NT inst = 4 rows x
        // 256B = 1KB (lq -> row group, l16 -> 16B col group).
        #pragma unroll
        for (int k = 0; k < 4; ++k) {
            int row = k * 4 + lq;
            f32x4 v = *(const f32x4*)&buf[row * CPAD + l16 * 4];
            __builtin_nontemporal_store(
                v, (f32x4*)&out[(size_t)(rbase + row) * OUTF + c0 + l16 * 4]);
        }
    }
}

extern "C" void kernel_launch(void* const* d_in, const int* in_sizes, int n_in,
                              void* d_out, int out_size, void* d_ws, size_t ws_size,
                              hipStream_t stream) {
    const float* x = (const float*)d_in[0];
    const float* w = (const float*)d_in[1];
    float* out = (float*)d_out;

    // ws layout: w2 [1024 f32] at 0; wb (frag-order bf16 W, 256KB) at 4096.
    char* ws = (char*)d_ws;
    float* w2 = (float*)ws;
    uint32_t* wb_u32 = (uint32_t*)(ws + 4096);
    const __bf16* wb = (const __bf16*)wb_u32;

    wprep_kernel<<<dim3(OUTF / 4), dim3(256), 0, stream>>>(w, w2, wb_u32);
    fused_kernel<<<dim3(BATCH / 16), dim3(512), 0, stream>>>(x, wb, w2, out);
}

// Round 23
// 73.366 us; speedup vs baseline: 3.1424x; 1.2393x over previous
//
#include <hip/hip_runtime.h>
#include <stdint.h>
#include <stddef.h>

#define BATCH 65536
#define OUTF  1024
#define INF   128

typedef float f32x4 __attribute__((ext_vector_type(4)));
typedef __bf16 bf16x8 __attribute__((ext_vector_type(8)));

#define CPAD 132   // wave scratch row stride (floats): 128 + 4

// RNE float->bf16, packed pair
__device__ inline uint32_t pack_bf16_rne(float a, float b) {
    uint32_t ua = __builtin_bit_cast(uint32_t, a);
    uint32_t ub = __builtin_bit_cast(uint32_t, b);
    ua += 0x7fffu + ((ua >> 16) & 1u);
    ub += 0x7fffu + ((ub >> 16) & 1u);
    return (ua >> 16) | (ub & 0xffff0000u);
}

// Load 8 contiguous fp32, accumulate sum of squares, return bf16x8 fragment.
__device__ inline bf16x8 load_frag_x2(const float* __restrict__ p, float& s) {
    f32x4 v0 = *(const f32x4*)(p);
    f32x4 v1 = *(const f32x4*)(p + 4);
    s += v0.x * v0.x + v0.y * v0.y + v0.z * v0.z + v0.w * v0.w
       + v1.x * v1.x + v1.y * v1.y + v1.z * v1.z + v1.w * v1.w;
    union { uint32_t u[4]; bf16x8 b; } f;
    f.u[0] = pack_bf16_rne(v0.x, v0.y);
    f.u[1] = pack_bf16_rne(v0.z, v0.w);
    f.u[2] = pack_bf16_rne(v1.x, v1.y);
    f.u[3] = pack_bf16_rne(v1.z, v1.w);
    return f.b;
}

// W prep: one wave per w-row. Writes wb in MFMA FRAGMENT ORDER (R14-verified)
// + row sumsq. Tile t=row>>4, ks=k>>5, frag-lane wl=((k>>3)&3)*16+(row&15),
// elem j=k&7: bf16 addr = ((t*4+ks)*64 + wl)*8 + j -> GEMM B-fragment load
// is ONE contiguous 1KB instruction.
__global__ __launch_bounds__(256) void wprep_kernel(
        const float* __restrict__ w, float* __restrict__ w2,
        uint32_t* __restrict__ wb) {
    int gtid = blockIdx.x * 256 + threadIdx.x;
    int row  = gtid >> 6;
    int lane = threadIdx.x & 63;
    if (row >= OUTF) return;
    const float* src = w + (size_t)row * INF;
    float2 v = *(const float2*)(src + lane * 2);   // k = 2*lane, 2*lane+1
    int t    = row >> 4;
    int l16r = row & 15;
    int ks   = lane >> 4;
    int lq   = (lane >> 2) & 3;
    int sub  = lane & 3;
    wb[(((size_t)t * 4 + ks) * 64 + lq * 16 + l16r) * 4 + sub] =
        pack_bf16_rne(v.x, v.y);
    float s = v.x * v.x + v.y * v.y;
    #pragma unroll
    for (int off = 32; off; off >>= 1) s += __shfl_down(s, off);
    if (lane == 0) w2[row] = s;
}

// Fused kernel (R20 + bijective XCD-chunked block swizzle): block = 16
// x-rows x ALL 1024 cols (grid 4096, 4/CU). With the swizzle, XCD k owns
// blocks [512k, 512k+512) -> a CONTIGUOUS 32MB output window per XCD,
// swept ~linearly by its resident blocks (fillBuffer-like write-stream
// partitioning). Everything else identical to R20: in-block 1x x-cvt,
// frag-order wb 1KB B-loads, wave-private LDS epilogue, paired
// 512B-segment NT stores, ONE barrier.
__global__ __launch_bounds__(256, 4) void fused_kernel(
        const float* __restrict__ x, const __bf16* __restrict__ wb,
        const float* __restrict__ w2, float* __restrict__ out) {
    // bijective XCD swizzle: 4096 blocks, 8 XCDs, 512 per XCD.
    int bid = blockIdx.x;
    int swz = (bid & 7) * 512 + (bid >> 3);

    int tid  = threadIdx.x;
    int wid  = tid >> 6;        // wave -> col slice [wid*256, wid*256+256)
    int lane = tid & 63;
    int l16  = lane & 15;       // fragment row/col
    int lq   = lane >> 4;       // k-quarter (loads) / row-quad (epilogue)

    int rbase = swz * 16;       // block's 16 x-rows

    __shared__ float sw2[OUTF];
    __shared__ float scratch[4][16 * CPAD];   // per-wave [16][132]
    #pragma unroll
    for (int j = 0; j < 4; ++j)
        sw2[tid + 256 * j] = w2[tid + 256 * j];

    // A fragments: 16 rows, k = ks*32 + lq*8 (16 VGPR) + x2 partial.
    bf16x8 a[4];
    float x2p = 0.f;
    #pragma unroll
    for (int ks = 0; ks < 4; ++ks)
        a[ks] = load_frag_x2(
            &x[(size_t)(rbase + l16) * INF + ks * 32 + lq * 8], x2p);

    // Row sumsq butterfly over k-quarter groups; redistribute to epilogue rows.
    x2p += __shfl_xor(x2p, 16);
    x2p += __shfl_xor(x2p, 32);
    float x2row[4];
    #pragma unroll
    for (int r = 0; r < 4; ++r)
        x2row[r] = __shfl(x2p, lq * 20 + r);

    __syncthreads();   // sw2 ready — the ONLY barrier

    float* buf = scratch[wid];

    #pragma unroll
    for (int sc = 0; sc < 4; ++sc) {
        int c0  = wid * 256 + sc * 64;          // sub-chunk column base
        int tb0 = c0 >> 4;                      // fragment-tile base
        int cb  = (sc & 1) * 64;                // column offset within buf

        f32x4 acc[4];
        #pragma unroll
        for (int in = 0; in < 4; ++in)
            acc[in] = f32x4{0.f, 0.f, 0.f, 0.f};

        #pragma unroll
        for (int ks = 0; ks < 4; ++ks) {
            bf16x8 b[4];
            #pragma unroll
            for (int in = 0; in < 4; ++in)
                b[in] = *(const bf16x8*)(
                    wb + (((size_t)(tb0 + in) * 4 + ks) << 9) + lane * 8);
            #pragma unroll
            for (int in = 0; in < 4; ++in)
                acc[in] = __builtin_amdgcn_mfma_f32_16x16x32_bf16(
                    a[ks], b[in], acc[in], 0, 0, 0);
        }

        // Epilogue into wave-private scratch (C/D: col=l16, row=lq*4+r).
        #pragma unroll
        for (int in = 0; in < 4; ++in) {
            #pragma unroll
            for (int r = 0; r < 4; ++r) {
                int row = lq * 4 + r;                 // 0..15
                int col = cb + in * 16 + l16;         // 0..127
                float d2 = x2row[r] + sw2[c0 + col - cb] - 2.0f * acc[in][r];
                buf[row * CPAD + col] =
                    -0.5f * __builtin_amdgcn_sqrtf(fmaxf(d2, 0.0f));
            }
        }
        // Intra-wave ds_write->ds_read ordering via lgkmcnt; no barrier.

        // After each PAIR of sub-chunks: store 16 rows x 512B segments.
        // Each NT inst = 1KB = 2 rows x 512B.
        if (sc & 1) {
            int cp0 = wid * 256 + (sc >> 1) * 128;
            #pragma unroll
            for (int k = 0; k < 8; ++k) {
                int row = k * 2 + (lane >> 5);
                f32x4 v = *(const f32x4*)&buf[row * CPAD + (lane & 31) * 4];
                __builtin_nontemporal_store(
                    v, (f32x4*)&out[(size_t)(rbase + row) * OUTF + cp0 + (lane & 31) * 4]);
            }
        }
    }
}

extern "C" void kernel_launch(void* const* d_in, const int* in_sizes, int n_in,
                              void* d_out, int out_size, void* d_ws, size_t ws_size,
                              hipStream_t stream) {
    const float* x = (const float*)d_in[0];
    const float* w = (const float*)d_in[1];
    float* out = (float*)d_out;

    // ws layout: w2 [1024 f32] at 0; wb (frag-order bf16 W, 256KB) at 4096.
    char* ws = (char*)d_ws;
    float* w2 = (float*)ws;
    uint32_t* wb_u32 = (uint32_t*)(ws + 4096);
    const __bf16* wb = (const __bf16*)wb_u32;

    wprep_kernel<<<dim3(OUTF / 4), dim3(256), 0, stream>>>(w, w2, wb_u32);
    fused_kernel<<<dim3(BATCH / 16), dim3(256), 0, stream>>>(x, wb, w2, out);
}

// Round 24
// 73.077 us; speedup vs baseline: 3.1548x; 1.0040x over previous
//
#include <hip/hip_runtime.h>
#include <stdint.h>
#include <stddef.h>

#define BATCH 65536
#define OUTF  1024
#define INF   128

typedef float f32x4 __attribute__((ext_vector_type(4)));
typedef __bf16 bf16x8 __attribute__((ext_vector_type(8)));

#define CPAD 68   // wave scratch row stride (floats): 64 + 4

// RNE float->bf16, packed pair
__device__ inline uint32_t pack_bf16_rne(float a, float b) {
    uint32_t ua = __builtin_bit_cast(uint32_t, a);
    uint32_t ub = __builtin_bit_cast(uint32_t, b);
    ua += 0x7fffu + ((ua >> 16) & 1u);
    ub += 0x7fffu + ((ub >> 16) & 1u);
    return (ua >> 16) | (ub & 0xffff0000u);
}

// Load 8 contiguous fp32, accumulate sum of squares, return bf16x8 fragment.
__device__ inline bf16x8 load_frag_x2(const float* __restrict__ p, float& s) {
    f32x4 v0 = *(const f32x4*)(p);
    f32x4 v1 = *(const f32x4*)(p + 4);
    s += v0.x * v0.x + v0.y * v0.y + v0.z * v0.z + v0.w * v0.w
       + v1.x * v1.x + v1.y * v1.y + v1.z * v1.z + v1.w * v1.w;
    union { uint32_t u[4]; bf16x8 b; } f;
    f.u[0] = pack_bf16_rne(v0.x, v0.y);
    f.u[1] = pack_bf16_rne(v0.z, v0.w);
    f.u[2] = pack_bf16_rne(v1.x, v1.y);
    f.u[3] = pack_bf16_rne(v1.z, v1.w);
    return f.b;
}

// W prep: one wave per w-row. Writes wb in MFMA FRAGMENT ORDER (R14-verified)
// + row sumsq. Tile t=row>>4, ks=k>>5, frag-lane wl=((k>>3)&3)*16+(row&15),
// elem j=k&7: bf16 addr = ((t*4+ks)*64 + wl)*8 + j -> GEMM B-fragment load
// is ONE contiguous 1KB instruction.
__global__ __launch_bounds__(256) void wprep_kernel(
        const float* __restrict__ w, float* __restrict__ w2,
        uint32_t* __restrict__ wb) {
    int gtid = blockIdx.x * 256 + threadIdx.x;
    int row  = gtid >> 6;
    int lane = threadIdx.x & 63;
    if (row >= OUTF) return;
    const float* src = w + (size_t)row * INF;
    float2 v = *(const float2*)(src + lane * 2);   // k = 2*lane, 2*lane+1
    int t    = row >> 4;
    int l16r = row & 15;
    int ks   = lane >> 4;
    int lq   = (lane >> 2) & 3;
    int sub  = lane & 3;
    wb[(((size_t)t * 4 + ks) * 64 + lq * 16 + l16r) * 4 + sub] =
        pack_bf16_rne(v.x, v.y);
    float s = v.x * v.x + v.y * v.y;
    #pragma unroll
    for (int off = 32; off; off >>= 1) s += __shfl_down(s, off);
    if (lane == 0) w2[row] = s;
}

// Fused kernel (R20 + shared-B 32-row blocks): block = 32 x-rows x ALL 1024
// cols (grid 2048, 4/CU), processed as TWO 16-row tiles that SHARE each
// B-fragment load (loop: sc -> ks -> {load b once, MFMA both tiles}) ->
// B L2 traffic halves (1GB -> 0.5GB aggregate). x converted in-block once;
// epilogue -> wave-private LDS scratch per tile; NT f32x4 stores (256B
// segments, 1KB/inst) per sub-chunk. ONE barrier total.
__global__ __launch_bounds__(256, 4) void fused_kernel(
        const float* __restrict__ x, const __bf16* __restrict__ wb,
        const float* __restrict__ w2, float* __restrict__ out) {
    int tid  = threadIdx.x;
    int wid  = tid >> 6;        // wave -> col slice [wid*256, wid*256+256)
    int lane = tid & 63;
    int l16  = lane & 15;       // fragment row/col
    int lq   = lane >> 4;       // k-quarter (loads) / row-quad (epilogue)

    int rbase = blockIdx.x * 32;   // block's 32 x-rows (2 tiles of 16)

    __shared__ float sw2[OUTF];
    __shared__ float scratch[4][2][16 * CPAD];   // [wave][tile][row][col]
    #pragma unroll
    for (int j = 0; j < 4; ++j)
        sw2[tid + 256 * j] = w2[tid + 256 * j];

    // A fragments for both tiles: 2 x 4 ks (32 VGPR) + x2 partials.
    bf16x8 a[4][2];
    float x2p[2] = {0.f, 0.f};
    #pragma unroll
    for (int ks = 0; ks < 4; ++ks)
        #pragma unroll
        for (int g = 0; g < 2; ++g)
            a[ks][g] = load_frag_x2(
                &x[(size_t)(rbase + g * 16 + l16) * INF + ks * 32 + lq * 8],
                x2p[g]);

    // Row sumsq butterfly; redistribute to epilogue rows lq*4+r.
    #pragma unroll
    for (int g = 0; g < 2; ++g) {
        float s = x2p[g];
        s += __shfl_xor(s, 16);
        s += __shfl_xor(s, 32);
        x2p[g] = s;
    }
    float x2row[2][4];
    #pragma unroll
    for (int g = 0; g < 2; ++g)
        #pragma unroll
        for (int r = 0; r < 4; ++r)
            x2row[g][r] = __shfl(x2p[g], lq * 20 + r);

    __syncthreads();   // sw2 ready — the ONLY barrier

    #pragma unroll
    for (int sc = 0; sc < 4; ++sc) {
        int c0  = wid * 256 + sc * 64;          // sub-chunk column base
        int tb0 = c0 >> 4;                      // fragment-tile base

        f32x4 acc[2][4];
        #pragma unroll
        for (int g = 0; g < 2; ++g)
            #pragma unroll
            for (int in = 0; in < 4; ++in)
                acc[g][in] = f32x4{0.f, 0.f, 0.f, 0.f};

        #pragma unroll
        for (int ks = 0; ks < 4; ++ks) {
            bf16x8 b[4];
            #pragma unroll
            for (int in = 0; in < 4; ++in)
                b[in] = *(const bf16x8*)(
                    wb + (((size_t)(tb0 + in) * 4 + ks) << 9) + lane * 8);
            #pragma unroll
            for (int g = 0; g < 2; ++g)
                #pragma unroll
                for (int in = 0; in < 4; ++in)
                    acc[g][in] = __builtin_amdgcn_mfma_f32_16x16x32_bf16(
                        a[ks][g], b[in], acc[g][in], 0, 0, 0);
        }

        // Epilogue both tiles into wave-private scratch (C/D: col=l16,
        // row=lq*4+r), then NT stores (256B segments, 1KB/inst).
        #pragma unroll
        for (int g = 0; g < 2; ++g) {
            float* buf = scratch[wid][g];
            #pragma unroll
            for (int in = 0; in < 4; ++in) {
                #pragma unroll
                for (int r = 0; r < 4; ++r) {
                    int row = lq * 4 + r;                 // 0..15
                    int col = in * 16 + l16;              // 0..63
                    float d2 = x2row[g][r] + sw2[c0 + col] - 2.0f * acc[g][in][r];
                    buf[row * CPAD + col] =
                        -0.5f * __builtin_amdgcn_sqrtf(fmaxf(d2, 0.0f));
                }
            }
        }
        // Intra-wave ds_write->ds_read ordering via lgkmcnt; no barrier.
        #pragma unroll
        for (int g = 0; g < 2; ++g) {
            float* buf = scratch[wid][g];
            #pragma unroll
            for (int k = 0; k < 4; ++k) {
                int row = k * 4 + lq;
                f32x4 v = *(const f32x4*)&buf[row * CPAD + l16 * 4];
                __builtin_nontemporal_store(
                    v, (f32x4*)&out[(size_t)(rbase + g * 16 + row) * OUTF + c0 + l16 * 4]);
            }
        }
    }
}

extern "C" void kernel_launch(void* const* d_in, const int* in_sizes, int n_in,
                              void* d_out, int out_size, void* d_ws, size_t ws_size,
                              hipStream_t stream) {
    const float* x = (const float*)d_in[0];
    const float* w = (const float*)d_in[1];
    float* out = (float*)d_out;

    // ws layout: w2 [1024 f32] at 0; wb (frag-order bf16 W, 256KB) at 4096.
    char* ws = (char*)d_ws;
    float* w2 = (float*)ws;
    uint32_t* wb_u32 = (uint32_t*)(ws + 4096);
    const __bf16* wb = (const __bf16*)wb_u32;

    wprep_kernel<<<dim3(OUTF / 4), dim3(256), 0, stream>>>(w, w2, wb_u32);
    fused_kernel<<<dim3(BATCH / 32), dim3(256), 0, stream>>>(x, wb, w2, out);
}